// Round 1
// baseline (702.106 us; speedup 1.0000x reference)
//
#include <hip/hip_runtime.h>

// Problem constants
#define B_    4096
#define T_    32
#define ADIM_ 64
#define HID_  128
#define E_    16
#define R_    32
#define OUT_  8
#define K_    256      // EA*EO
#define BTILE 32       // b-rows per block
#define NBLK  (B_ / BTILE)   // 128 main-kernel blocks

typedef _Float16 f16;
typedef _Float16 f16x2 __attribute__((ext_vector_type(2)));
typedef _Float16 f16x4 __attribute__((ext_vector_type(4)));
typedef _Float16 f16x8 __attribute__((ext_vector_type(8)));
typedef float    f32x4 __attribute__((ext_vector_type(4)));

#define GPTR(p) ((const __attribute__((address_space(1))) void*)(p))
#define LPTR(p) ((__attribute__((address_space(3))) void*)(p))

// ---- workspace layout (bytes). Total required ~32.7 MB ----
#define WS_WA   0u                       // 1024 f32: fused Wa0@Wa1  [64][16]
#define WS_WO   4096u                    // 1024 f32
#define WS_BA   8192u                    // 16 f32 fused action bias
#define WS_BO   8448u                    // 16 f32
#define WS_AENC 16384u                   // [B][T][16] f32 = 8 MB
#define WS_OENC (WS_AENC + 8388608u)     // 8 MB
#define WS_H    (WS_OENC + 8388608u)     // f16 relaid H, ~15.9 MB

// H region: per t: 8 slabs (one per 32-wide K-step); slab = ncount rows x 64B
// row n holds its 32 f16 (k32) XOR-swizzled: f16 k32 at byte ((k32>>2)^(n&7))*8 + (k32&3)*2
__device__ __host__ __forceinline__ size_t hoff_t(int t) {
  if (t == 0)  return 0;
  if (t == 31) return 16384u + 30u * 524288u;
  return 16384u + (size_t)(t - 1) * 524288u;
}
__device__ __forceinline__ int ncount_t(int t) { return t == 0 ? 32 : (t == 31 ? 256 : 1024); }

// ------------------- prep 1: fuse encoder weights -------------------
__global__ void k_fuse_w(const float* __restrict__ Wa0, const float* __restrict__ ba0,
                         const float* __restrict__ Wa1, const float* __restrict__ ba1,
                         const float* __restrict__ Wo0, const float* __restrict__ bo0,
                         const float* __restrict__ Wo1, const float* __restrict__ bo1,
                         float* __restrict__ ws) {
  const int tid = threadIdx.x;  // 256 threads, 1 block
  float* WA = ws;
  float* WO = ws + 1024;
  float* BA = ws + 2048;
  float* BO = ws + 2048 + 64;
  for (int idx = tid; idx < 1024; idx += 256) {
    const int d = idx >> 4, j = idx & 15;
    float s = 0.f, s2 = 0.f;
    for (int h = 0; h < HID_; ++h) {
      s  += Wa0[d * HID_ + h] * Wa1[h * E_ + j];
      s2 += Wo0[d * HID_ + h] * Wo1[h * E_ + j];
    }
    WA[idx] = s;
    WO[idx] = s2;
  }
  if (tid < 16) {
    float s = 0.f, s2 = 0.f;
    for (int h = 0; h < HID_; ++h) {
      s  += ba0[h] * Wa1[h * E_ + tid];
      s2 += bo0[h] * Wo1[h * E_ + tid];
    }
    BA[tid] = s + ba1[tid];
    BO[tid] = s2 + bo1[tid];
  }
}

// ------------------- prep 2: encode a,o (fp32) -------------------
__global__ void k_encode(const float* __restrict__ action, const float* __restrict__ obs,
                         const float* __restrict__ ws,
                         float* __restrict__ aenc, float* __restrict__ oenc) {
  const int f  = blockIdx.x * 256 + threadIdx.x;  // f < B*T*16
  const int j  = f & 15;
  const int bt = f >> 4;
  const float* arow = action + (size_t)bt * ADIM_;
  const float* orow = obs    + (size_t)bt * ADIM_;
  const float* WA = ws;
  const float* WO = ws + 1024;
  float sa = ws[2048 + j];
  float so = ws[2048 + 64 + j];
  for (int d = 0; d < ADIM_; ++d) {
    sa += arow[d] * WA[d * 16 + j];
    so += orow[d] * WO[d * 16 + j];
  }
  aenc[f] = sa;
  oenc[f] = so;
}

// ------------------- prep 3: relayout H -> f16, [t][kstep][n][swizzled 32k] -------------------
// n = l*32+p (mid), n=l (t=0), n=o*32+p (t=31); k = j*16+kk (j action-idx, kk obs-idx)
__global__ void k_hprep(const float* __restrict__ Hf, const float* __restrict__ Hm,
                        const float* __restrict__ Hl, char* __restrict__ hdst) {
  const int t = blockIdx.y;
  const int nc = ncount_t(t);
  const int idx = blockIdx.x * 256 + threadIdx.x;
  if (idx >= nc * K_) return;
  const int n = idx >> 8, k = idx & 255;
  const int j = k >> 4, kk = k & 15;
  float v;
  if (t == 0) {
    v = Hf[(j * 16 + kk) * 32 + n];
  } else if (t == 31) {
    const int p = n & 31, o = n >> 5;
    v = Hl[((p * 16 + j) * 16 + kk) * 8 + o];
  } else {
    const int p = n & 31, l = n >> 5;
    v = Hm[((((size_t)(t - 1) * 32 + p) * 16 + j) * 16 + kk) * 32 + l];
  }
  const int s = k >> 5, k32 = k & 31;
  const size_t slab = hoff_t(t) + (size_t)s * (nc * 64);
  const size_t off = slab + (size_t)n * 64 + (size_t)((((k32 >> 2) ^ (n & 7)) << 3) + ((k32 & 3) << 1));
  *(f16*)(hdst + off) = (f16)v;
}

// ------------------- main fused kernel -------------------
// 128 blocks x 256 threads; block owns 32 b-rows for all 32 timesteps.
// LDS: double-buffered 64KB H slabs (async global_load_lds, swizzle pre-baked in ws),
// E fragments, fp32 chain state. Chain update via 16-lane shuffle butterflies.
__launch_bounds__(256, 1)
__global__ void k_main(const float* __restrict__ aenc, const float* __restrict__ oenc,
                       const char* __restrict__ hbase, float* __restrict__ out) {
  __shared__ __align__(16) char Hlds[2][65536];     // 128 KB
  __shared__ __align__(16) f16  Ebuf[BTILE][264];   // 16.5 KB (row pad 8 f16)
  __shared__ float cbuf[2][BTILE][32];              // 8 KB

  const int tid  = threadIdx.x;
  const int lane = tid & 63;
  const int w    = tid >> 6;     // wave 0..3
  const int m16  = lane & 15;
  const int g4   = lane >> 4;    // 0..3
  const int b0   = blockIdx.x * BTILE;
  const int jj   = tid & 15;     // E-build col group

  // prologue: stage slab q=0 (t=0, s=0; 2048 bytes)
  {
    const char* src = hbase;
    for (int base = w * 1024; base < 2048; base += 4096) {
      __builtin_amdgcn_global_load_lds(GPTR(src + base + lane * 16), LPTR(&Hlds[0][base]), 16, 0, 0);
    }
  }
  asm volatile("s_waitcnt vmcnt(0)" ::: "memory");
  __syncthreads();

  int par = 0;

  for (int t = 0; t < T_; ++t) {
    // ---- build E (fp16) for this t: E[b][j*16+kk] = a[b][j]*o[b][kk] ----
    #pragma unroll
    for (int rr = 0; rr < BTILE; rr += 16) {
      const int row = (tid >> 4) + rr;
      const float av = aenc[((size_t)(b0 + row) * T_ + t) * 16 + jj];
      const float* orow = &oenc[((size_t)(b0 + row) * T_ + t) * 16];
      #pragma unroll
      for (int kk = 0; kk < 16; kk += 2) {
        f16x2 p;
        p[0] = (f16)(av * orow[kk]);
        p[1] = (f16)(av * orow[kk + 1]);
        *(f16x2*)&Ebuf[row][jj * 16 + kk] = p;
      }
    }
    __syncthreads();

    // ---- preload A fragments (two k-half layout; any consistent bijection is valid
    //      since A and B share the same per-lane k convention) ----
    f16x8 afr[2][8];
    #pragma unroll
    for (int mf = 0; mf < 2; ++mf) {
      #pragma unroll
      for (int s = 0; s < 8; ++s) {
        const f16* bp = &Ebuf[mf * 16 + m16][s * 32 + g4 * 4];
        const f16x4 lo = *(const f16x4*)bp;
        const f16x4 hi = *(const f16x4*)(bp + 16);
        afr[mf][s][0] = lo[0]; afr[mf][s][1] = lo[1]; afr[mf][s][2] = lo[2]; afr[mf][s][3] = lo[3];
        afr[mf][s][4] = hi[0]; afr[mf][s][5] = hi[1]; afr[mf][s][6] = hi[2]; afr[mf][s][7] = hi[3];
      }
    }

    f32x4 acc[2][16];
    #pragma unroll
    for (int mf = 0; mf < 2; ++mf)
      #pragma unroll
      for (int i = 0; i < 16; ++i) acc[mf][i] = (f32x4){0.f, 0.f, 0.f, 0.f};

    int nfc, nbase0;
    if (t == 0)       { nfc = (w == 0) ? 2 : 0; nbase0 = 0; }
    else if (t == 31) { nfc = 4;  nbase0 = w * 64; }
    else              { nfc = 16; nbase0 = w * 256; }

    // ---- K loop: 8 slabs, double-buffered ----
    #pragma unroll
    for (int s = 0; s < 8; ++s) {
      const int q = t * 8 + s;
      if (q + 1 < 256) {  // stage next slab into alternate buffer
        const int t2 = (q + 1) >> 3, s2 = (q + 1) & 7;
        const int bytes2 = ncount_t(t2) << 6;
        const char* src = hbase + hoff_t(t2) + (size_t)s2 * bytes2;
        for (int base = w * 1024; base < bytes2; base += 4096) {
          __builtin_amdgcn_global_load_lds(GPTR(src + base + lane * 16),
                                           LPTR(&Hlds[(s + 1) & 1][base]), 16, 0, 0);
        }
      }
      #pragma unroll
      for (int i = 0; i < 16; ++i) {
        if (i < nfc) {
          const int n = nbase0 + i * 16 + m16;
          const int swz = n & 7;
          const int ro = n * 64;
          const f16x4 blo = *(const f16x4*)&Hlds[s & 1][ro + ((g4 ^ swz) << 3)];
          const f16x4 bhi = *(const f16x4*)&Hlds[s & 1][ro + (((4 + g4) ^ swz) << 3)];
          f16x8 bf;
          bf[0] = blo[0]; bf[1] = blo[1]; bf[2] = blo[2]; bf[3] = blo[3];
          bf[4] = bhi[0]; bf[5] = bhi[1]; bf[6] = bhi[2]; bf[7] = bhi[3];
          acc[0][i] = __builtin_amdgcn_mfma_f32_16x16x32_f16(afr[0][s], bf, acc[0][i], 0, 0, 0);
          acc[1][i] = __builtin_amdgcn_mfma_f32_16x16x32_f16(afr[1][s], bf, acc[1][i], 0, 0, 0);
        }
      }
      asm volatile("s_waitcnt vmcnt(0)" ::: "memory");
      __syncthreads();
    }

    // ---- chain update ----
    // D layout: row(b within mfrag) = g4*4+reg, col(n) = m16  [m89-verified]
    if (t == 0) {
      if (w == 0) {
        #pragma unroll
        for (int i = 0; i < 2; ++i)
          #pragma unroll
          for (int mf = 0; mf < 2; ++mf)
            #pragma unroll
            for (int r = 0; r < 4; ++r)
              cbuf[0][mf * 16 + g4 * 4 + r][i * 16 + m16] = acc[mf][i][r];
      }
      par = 0;
    } else {
      const int npairs = (t == 31) ? 2 : 8;
      const int obase  = nbase0 >> 5;   // output l (or o) base for this wave
      #pragma unroll
      for (int u = 0; u < 8; ++u) {
        if (u < npairs) {
          #pragma unroll
          for (int mf = 0; mf < 2; ++mf) {
            float v[4];
            #pragma unroll
            for (int r = 0; r < 4; ++r) {
              const int b = mf * 16 + g4 * 4 + r;
              v[r] = acc[mf][2 * u][r]     * cbuf[par][b][m16]
                   + acc[mf][2 * u + 1][r] * cbuf[par][b][16 + m16];
            }
            #pragma unroll
            for (int off = 1; off < 16; off <<= 1)
              #pragma unroll
              for (int r = 0; r < 4; ++r) v[r] += __shfl_xor(v[r], off, 16);
            if (t == 31) {
              if (m16 == 0) {
                #pragma unroll
                for (int r = 0; r < 4; ++r)
                  out[(size_t)(b0 + mf * 16 + g4 * 4 + r) * OUT_ + (obase + u)] = v[r];
              }
            } else {
              if (m16 == 0) {
                #pragma unroll
                for (int r = 0; r < 4; ++r)
                  cbuf[par ^ 1][mf * 16 + g4 * 4 + r][obase + u] = v[r];
              }
            }
          }
        }
      }
      if (t != 31) par ^= 1;
    }
    // no trailing barrier needed: next-t E-build barrier + k-loop barriers order cbuf accesses
  }
}

extern "C" void kernel_launch(void* const* d_in, const int* in_sizes, int n_in,
                              void* d_out, int out_size, void* d_ws, size_t ws_size,
                              hipStream_t stream) {
  const float* action = (const float*)d_in[0];
  const float* obs    = (const float*)d_in[1];
  const float* Wa0 = (const float*)d_in[2];
  const float* ba0 = (const float*)d_in[3];
  const float* Wa1 = (const float*)d_in[4];
  const float* ba1 = (const float*)d_in[5];
  const float* Wo0 = (const float*)d_in[6];
  const float* bo0 = (const float*)d_in[7];
  const float* Wo1 = (const float*)d_in[8];
  const float* bo1 = (const float*)d_in[9];
  const float* Hf  = (const float*)d_in[10];
  const float* Hm  = (const float*)d_in[11];
  const float* Hl  = (const float*)d_in[12];
  char*  ws  = (char*)d_ws;
  float* out = (float*)d_out;

  k_fuse_w<<<1, 256, 0, stream>>>(Wa0, ba0, Wa1, ba1, Wo0, bo0, Wo1, bo1, (float*)ws);
  k_encode<<<(B_ * T_ * 16) / 256, 256, 0, stream>>>(action, obs, (const float*)ws,
                                                     (float*)(ws + WS_AENC), (float*)(ws + WS_OENC));
  k_hprep<<<dim3(1024, 32), 256, 0, stream>>>(Hf, Hm, Hl, ws + WS_H);
  k_main<<<NBLK, 256, 0, stream>>>((const float*)(ws + WS_AENC), (const float*)(ws + WS_OENC),
                                   (const char*)(ws + WS_H), out);
}

// Round 2
// 355.363 us; speedup vs baseline: 1.9757x; 1.9757x over previous
//
#include <hip/hip_runtime.h>

// Problem constants
#define B_    4096
#define T_    32
#define ADIM_ 64
#define HID_  128
#define E_    16
#define R_    32
#define OUT_  8
#define BTILE 16
#define NBLK  (B_ / BTILE)   // 256 main-kernel blocks

typedef _Float16 f16;
typedef _Float16 f16x4 __attribute__((ext_vector_type(4)));
typedef _Float16 f16x8 __attribute__((ext_vector_type(8)));
typedef float    f32x4 __attribute__((ext_vector_type(4)));

// ---- workspace layout (bytes). Total ~25.2 MB ----
// weights: [0, 8448) f32 (WA 1024, WO 1024, BA 16 @f32idx2048, BO 16 @f32idx2112)
#define WS_AENC 16384u                    // [B][T][16] f16 = 4 MB
#define WS_OENC (WS_AENC + 4194304u)      // 4 MB
#define WS_H    (WS_OENC + 4194304u)      // f16 relaid H: [32 t][8 s][64 KB slab] = 16 MB
// slab layout: 1 KB block per (w,i16): granule for (n = w*256+i16*16+m16, g4) at
//   byte  w*16384 + i16*1024 + (g4*16+m16)*16 ,  content f16[8]: slot h*4+r = H[n][k32=h*16+g4*4+r]

// ------------------- prep 1: fuse encoder weights -------------------
__global__ void k_fuse_w(const float* __restrict__ Wa0, const float* __restrict__ ba0,
                         const float* __restrict__ Wa1, const float* __restrict__ ba1,
                         const float* __restrict__ Wo0, const float* __restrict__ bo0,
                         const float* __restrict__ Wo1, const float* __restrict__ bo1,
                         float* __restrict__ ws) {
  const int tid = threadIdx.x;  // 256 threads, 1 block
  for (int idx = tid; idx < 1024; idx += 256) {
    const int d = idx >> 4, j = idx & 15;
    float s = 0.f, s2 = 0.f;
    for (int h = 0; h < HID_; ++h) {
      s  += Wa0[d * HID_ + h] * Wa1[h * E_ + j];
      s2 += Wo0[d * HID_ + h] * Wo1[h * E_ + j];
    }
    ws[idx] = s;
    ws[1024 + idx] = s2;
  }
  if (tid < 16) {
    float s = 0.f, s2 = 0.f;
    for (int h = 0; h < HID_; ++h) {
      s  += ba0[h] * Wa1[h * E_ + tid];
      s2 += bo0[h] * Wo1[h * E_ + tid];
    }
    ws[2048 + tid] = s + ba1[tid];
    ws[2048 + 64 + tid] = s2 + bo1[tid];
  }
}

// ------------------- prep 2: encode a,o -> f16 -------------------
__global__ void k_encode(const float* __restrict__ action, const float* __restrict__ obs,
                         const float* __restrict__ ws,
                         f16* __restrict__ aenc, f16* __restrict__ oenc) {
  const int f  = blockIdx.x * 256 + threadIdx.x;  // f < B*T*16
  const int j  = f & 15;
  const int bt = f >> 4;
  const float* arow = action + (size_t)bt * ADIM_;
  const float* orow = obs    + (size_t)bt * ADIM_;
  float sa = ws[2048 + j];
  float so = ws[2048 + 64 + j];
  for (int d = 0; d < ADIM_; ++d) {
    sa += arow[d] * ws[d * 16 + j];
    so += orow[d] * ws[1024 + d * 16 + j];
  }
  aenc[f] = (f16)sa;
  oenc[f] = (f16)so;
}

// ------------------- prep 3a: relayout mid cores (t = 1..30) -------------------
__global__ void k_hprep_mid(const float* __restrict__ Hm, char* __restrict__ hdst) {
  const int x = blockIdx.x * 256 + threadIdx.x;   // < 30*32768
  const int m16 = x & 15;
  const int g4  = (x >> 4) & 3;
  const int i16 = (x >> 6) & 15;
  const int w   = (x >> 10) & 3;
  const int s   = (x >> 12) & 7;
  const int t   = 1 + (x >> 15);
  const int p   = (i16 & 1) * 16 + m16;
  const int l   = w * 8 + (i16 >> 1);
  f16x8 g;
  #pragma unroll
  for (int h = 0; h < 2; ++h) {
    const size_t rowb = ((((size_t)(t - 1) * 32 + p) * 16 + (2 * s + h)) * 16) * 32;
    #pragma unroll
    for (int r = 0; r < 4; ++r)
      g[h * 4 + r] = (f16)Hm[rowb + (size_t)(g4 * 4 + r) * 32 + l];
  }
  char* dst = hdst + (size_t)t * 524288 + (size_t)s * 65536 + w * 16384 + i16 * 1024 + g4 * 256 + m16 * 16;
  *(f16x8*)dst = g;
}

// ------------------- prep 3b: relayout first/last cores -------------------
__global__ void k_hprep_edge(const float* __restrict__ Hf, const float* __restrict__ Hl,
                             char* __restrict__ hdst) {
  const int x = blockIdx.x * 256 + threadIdx.x;   // < 9216
  if (x < 1024) {
    // t = 0: n = l*32 (p==0 only)
    const int g4 = x & 3, s = (x >> 2) & 7, l = x >> 5;
    f16x8 g;
    #pragma unroll
    for (int h = 0; h < 2; ++h)
      #pragma unroll
      for (int r = 0; r < 4; ++r)
        g[h * 4 + r] = (f16)Hf[((2 * s + h) * 16 + g4 * 4 + r) * 32 + l];
    char* dst = hdst + (size_t)s * 65536 + (l >> 3) * 16384 + ((l & 7) * 2) * 1024 + g4 * 256;
    *(f16x8*)dst = g;
  } else {
    // t = 31: n = o*32 + p  (n < 256 -> w = 0)
    const int x2 = x - 1024;
    const int m16 = x2 & 15, g4 = (x2 >> 4) & 3, s = (x2 >> 6) & 7, i16 = (x2 >> 9) & 15;
    const int p = (i16 & 1) * 16 + m16;
    const int o = i16 >> 1;
    f16x8 g;
    #pragma unroll
    for (int h = 0; h < 2; ++h)
      #pragma unroll
      for (int r = 0; r < 4; ++r)
        g[h * 4 + r] = (f16)Hl[((p * 16 + (2 * s + h)) * 16 + g4 * 4 + r) * 8 + o];
    char* dst = hdst + (size_t)31 * 524288 + (size_t)s * 65536 + i16 * 1024 + g4 * 256 + m16 * 16;
    *(f16x8*)dst = g;
  }
}

// ------------------- main fused kernel -------------------
// 256 blocks x 256 threads (4 waves, 1 block/CU). Wave w owns n in [w*256, w*256+256).
// H streamed global -> VGPR (rb double-buffer, compiler-managed vmcnt). LDS = chain state only.
__launch_bounds__(256)
__global__ void k_main(const f16* __restrict__ aenc, const f16* __restrict__ oenc,
                       const char* __restrict__ hws, float* __restrict__ out) {
  __shared__ float cbuf[2][BTILE][32];

  const int tid  = threadIdx.x;
  const int lane = tid & 63;
  const int w    = tid >> 6;
  const int m16  = lane & 15;
  const int g4   = lane >> 4;
  const int b0   = blockIdx.x * BTILE;

  // init chain state: c[b][p] = (p == 0)
  for (int k2 = tid; k2 < 512; k2 += 256)
    cbuf[0][k2 >> 5][k2 & 31] = ((k2 & 31) == 0) ? 1.f : 0.f;

  const char* hp = hws + (size_t)w * 16384 + (size_t)lane * 16;

  f16x8 rb[2][16];
  #pragma unroll
  for (int i = 0; i < 16; ++i) rb[0][i] = *(const f16x8*)(hp + i * 1024);

  asm volatile("s_waitcnt lgkmcnt(0)" ::: "memory");
  __builtin_amdgcn_s_barrier();

  int par = 0;
  #pragma clang loop unroll(disable)
  for (int t = 0; t < T_; ++t) {
    // per-lane E inputs: a-row m16 (16 f16), o-row m16 elems g4*4..+3
    const f16* ap = aenc + ((size_t)(b0 + m16) * T_ + t) * 16;
    const f16x8 av0 = *(const f16x8*)ap;
    const f16x8 av1 = *(const f16x8*)(ap + 8);
    const f16x4 ov  = *(const f16x4*)(oenc + ((size_t)(b0 + m16) * T_ + t) * 16 + g4 * 4);

    f32x4 acc[16];
    #pragma unroll
    for (int i = 0; i < 16; ++i) acc[i] = (f32x4){0.f, 0.f, 0.f, 0.f};

    const char* hq = hp + (size_t)t * 524288;
    #pragma unroll
    for (int s = 0; s < 8; ++s) {
      // prefetch slab q+1 into the other reg buffer (clamped on the very last slab)
      const char* hn = hq + (size_t)((t == 31 && s == 7) ? s : (s + 1)) * 65536;
      #pragma unroll
      for (int i = 0; i < 16; ++i)
        rb[(s + 1) & 1][i] = *(const f16x8*)(hn + i * 1024);

      // A fragment: slots 0-3 = a[2s]*o[r], slots 4-7 = a[2s+1]*o[r]
      const f16 a0 = (s < 4) ? av0[2 * (s & 3)]     : av1[2 * (s & 3)];
      const f16 a1 = (s < 4) ? av0[2 * (s & 3) + 1] : av1[2 * (s & 3) + 1];
      f16x8 af;
      af[0] = a0 * ov[0]; af[1] = a0 * ov[1]; af[2] = a0 * ov[2]; af[3] = a0 * ov[3];
      af[4] = a1 * ov[0]; af[5] = a1 * ov[1]; af[6] = a1 * ov[2]; af[7] = a1 * ov[3];

      #pragma unroll
      for (int i = 0; i < 16; ++i)
        acc[i] = __builtin_amdgcn_mfma_f32_16x16x32_f16(af, rb[s & 1][i], acc[i], 0, 0, 0);
    }

    // ---- chain update: c_new[b][l] = sum_p c[b][p] * M[b][p][l] ----
    // acc[i] covers n = w*256 + i*16 + m16 ; p = (i&1)*16+m16 ; l = w*8 + (i>>1)
    // D layout: b-row = g4*4+r, n-col = m16
    float cl[4], ch[4];
    #pragma unroll
    for (int r = 0; r < 4; ++r) {
      cl[r] = cbuf[par][g4 * 4 + r][m16];
      ch[r] = cbuf[par][g4 * 4 + r][16 + m16];
    }
    #pragma unroll
    for (int u = 0; u < 8; ++u) {
      float v[4];
      #pragma unroll
      for (int r = 0; r < 4; ++r)
        v[r] = acc[2 * u][r] * cl[r] + acc[2 * u + 1][r] * ch[r];
      #pragma unroll
      for (int off = 1; off < 16; off <<= 1)
        #pragma unroll
        for (int r = 0; r < 4; ++r) v[r] += __shfl_xor(v[r], off, 16);
      if (m16 == 0) {
        #pragma unroll
        for (int r = 0; r < 4; ++r)
          cbuf[par ^ 1][g4 * 4 + r][w * 8 + u] = v[r];
      }
    }
    par ^= 1;
    asm volatile("s_waitcnt lgkmcnt(0)" ::: "memory");
    __builtin_amdgcn_s_barrier();
  }

  // final: out[b][0..7] = cbuf[0][b][0..7]   (par toggled 32x -> back to 0)
  if (tid < 128)
    out[(size_t)(b0 + (tid >> 3)) * OUT_ + (tid & 7)] = cbuf[0][tid >> 3][tid & 7];
}

extern "C" void kernel_launch(void* const* d_in, const int* in_sizes, int n_in,
                              void* d_out, int out_size, void* d_ws, size_t ws_size,
                              hipStream_t stream) {
  (void)in_sizes; (void)n_in; (void)out_size; (void)ws_size;
  const float* action = (const float*)d_in[0];
  const float* obs    = (const float*)d_in[1];
  const float* Wa0 = (const float*)d_in[2];
  const float* ba0 = (const float*)d_in[3];
  const float* Wa1 = (const float*)d_in[4];
  const float* ba1 = (const float*)d_in[5];
  const float* Wo0 = (const float*)d_in[6];
  const float* bo0 = (const float*)d_in[7];
  const float* Wo1 = (const float*)d_in[8];
  const float* bo1 = (const float*)d_in[9];
  const float* Hf  = (const float*)d_in[10];
  const float* Hm  = (const float*)d_in[11];
  const float* Hl  = (const float*)d_in[12];
  char*  ws  = (char*)d_ws;
  float* out = (float*)d_out;

  k_fuse_w<<<1, 256, 0, stream>>>(Wa0, ba0, Wa1, ba1, Wo0, bo0, Wo1, bo1, (float*)ws);
  k_encode<<<(B_ * T_ * 16) / 256, 256, 0, stream>>>(action, obs, (const float*)ws,
                                                     (f16*)(ws + WS_AENC), (f16*)(ws + WS_OENC));
  // zero only the padded edge slabs (t=0 and t=31); mid region is fully overwritten
  hipMemsetAsync(ws + WS_H, 0, 524288, stream);
  hipMemsetAsync(ws + WS_H + (size_t)31 * 524288, 0, 524288, stream);
  k_hprep_mid<<<(30 * 32768) / 256, 256, 0, stream>>>(Hm, ws + WS_H);
  k_hprep_edge<<<9216 / 256, 256, 0, stream>>>(Hf, Hl, ws + WS_H);
  k_main<<<NBLK, 256, 0, stream>>>((const f16*)(ws + WS_AENC), (const f16*)(ws + WS_OENC),
                                   (const char*)(ws + WS_H), out);
}

// Round 3
// 231.986 us; speedup vs baseline: 3.0265x; 1.5318x over previous
//
#include <hip/hip_runtime.h>

// Problem constants
#define B_    4096
#define T_    32
#define OUT_  8
#define BTILE 32
#define NBLK  (B_ / BTILE)   // 128 main-kernel blocks

typedef _Float16 f16;
typedef _Float16 f16x4 __attribute__((ext_vector_type(4)));
typedef _Float16 f16x8 __attribute__((ext_vector_type(8)));
typedef float    f32x4 __attribute__((ext_vector_type(4)));

// ---- workspace layout (bytes). Total ~25.2 MB ----
// [0, 8448): f32 weights (WA 1024, WO 1024, biasA 16 @f32idx 2048, biasB 16 @f32idx 2112)
#define WS_AENC 16384u                    // [B*T][16] f16 = 4 MB
#define WS_OENC (WS_AENC + 4194304u)      // 4 MB
#define WS_H    (WS_OENC + 4194304u)      // f16 relaid H: 16 MB
// H granule (1 KB) per (t, p, s, nf): addr = (((t*32+p)*8+s)*2+nf)*1024
// granule byte (g4*16+m16)*16 + slot*2 ; slot h*4+r = Ht[p][j=2s+h][kk=g4*4+r][l=nf*16+m16] * (1/8)

// ------------------- prep 1: fuse encoder weights -------------------
__global__ void k_fuse_w(const float* __restrict__ Wa0, const float* __restrict__ ba0,
                         const float* __restrict__ Wa1, const float* __restrict__ ba1,
                         const float* __restrict__ Wo0, const float* __restrict__ bo0,
                         const float* __restrict__ Wo1, const float* __restrict__ bo1,
                         float* __restrict__ ws) {
  const int tid = threadIdx.x;  // 256 threads, 1 block
  for (int idx = tid; idx < 1024; idx += 256) {
    const int d = idx >> 4, j = idx & 15;
    float s = 0.f, s2 = 0.f;
    for (int h = 0; h < 128; ++h) {
      s  += Wa0[d * 128 + h] * Wa1[h * 16 + j];
      s2 += Wo0[d * 128 + h] * Wo1[h * 16 + j];
    }
    ws[idx] = s;
    ws[1024 + idx] = s2;
  }
  if (tid < 16) {
    float s = 0.f, s2 = 0.f;
    for (int h = 0; h < 128; ++h) {
      s  += ba0[h] * Wa1[h * 16 + tid];
      s2 += bo0[h] * Wo1[h * 16 + tid];
    }
    ws[2048 + tid] = s + ba1[tid];
    ws[2112 + tid] = s2 + bo1[tid];
  }
}

// ------------------- prep 2: MFMA encoder (f16 in, f32 acc) -------------------
// 2048 blocks x 256 threads; wave handles 16 bt-rows for both a and o.
__global__ void k_encode(const float* __restrict__ action, const float* __restrict__ obs,
                         const float* __restrict__ ws,
                         f16* __restrict__ aenc, f16* __restrict__ oenc) {
  const int tid = threadIdx.x;
  const int lane = tid & 63;
  const int v = tid >> 6;
  const int m16 = lane & 15, g4 = lane >> 4;
  const int bt0 = blockIdx.x * 64 + v * 16;

  f16x8 wbA[2], wbB[2];
  #pragma unroll
  for (int ks = 0; ks < 2; ++ks)
    #pragma unroll
    for (int h = 0; h < 2; ++h)
      #pragma unroll
      for (int r = 0; r < 4; ++r) {
        const int d = ks * 32 + h * 16 + g4 * 4 + r;
        wbA[ks][h * 4 + r] = (f16)ws[d * 16 + m16];
        wbB[ks][h * 4 + r] = (f16)ws[1024 + d * 16 + m16];
      }
  const float biasA = ws[2048 + m16], biasB = ws[2112 + m16];
  f32x4 accA = {biasA, biasA, biasA, biasA};
  f32x4 accB = {biasB, biasB, biasB, biasB};

  const float* ar = action + (size_t)(bt0 + m16) * 64;
  const float* br = obs    + (size_t)(bt0 + m16) * 64;
  #pragma unroll
  for (int ks = 0; ks < 2; ++ks) {
    f16x8 aa, oo;
    #pragma unroll
    for (int h = 0; h < 2; ++h) {
      const f32x4 a4 = *(const f32x4*)(ar + ks * 32 + h * 16 + g4 * 4);
      const f32x4 o4 = *(const f32x4*)(br + ks * 32 + h * 16 + g4 * 4);
      #pragma unroll
      for (int r = 0; r < 4; ++r) { aa[h * 4 + r] = (f16)a4[r]; oo[h * 4 + r] = (f16)o4[r]; }
    }
    accA = __builtin_amdgcn_mfma_f32_16x16x32_f16(aa, wbA[ks], accA, 0, 0, 0);
    accB = __builtin_amdgcn_mfma_f32_16x16x32_f16(oo, wbB[ks], accB, 0, 0, 0);
  }
  // D: col j = m16, rows bt0 + g4*4 + r
  #pragma unroll
  for (int r = 0; r < 4; ++r) {
    aenc[(size_t)(bt0 + g4 * 4 + r) * 16 + m16] = (f16)accA[r];
    oenc[(size_t)(bt0 + g4 * 4 + r) * 16 + m16] = (f16)accB[r];
  }
}

// ------------------- prep 3: relayout H -> f16 granules, scaled by 1/8 -------------------
__global__ void k_hprep(const float* __restrict__ Hf, const float* __restrict__ Hm,
                        const float* __restrict__ Hl, f16* __restrict__ hdst) {
  const int x = blockIdx.x * 256 + threadIdx.x;     // < 1048576
  const int lane = x & 63;
  const int gid = x >> 6;
  const int nf = gid & 1, s = (gid >> 1) & 7, p = (gid >> 4) & 31, t = gid >> 9;
  const int m16 = lane & 15, g4 = lane >> 4;
  const int l = nf * 16 + m16;
  f16x8 gout;
  #pragma unroll
  for (int h = 0; h < 2; ++h) {
    const int j = 2 * s + h;
    #pragma unroll
    for (int r = 0; r < 4; ++r) {
      const int kk = g4 * 4 + r;
      float vsrc;
      if (t == 0)       vsrc = (p == 0) ? Hf[(j * 16 + kk) * 32 + l] : 0.f;
      else if (t == 31) vsrc = (l < 8) ? Hl[((p * 16 + j) * 16 + kk) * 8 + l] : 0.f;
      else              vsrc = Hm[((((size_t)(t - 1) * 32 + p) * 16 + j) * 16 + kk) * 32 + l];
      gout[h * 4 + r] = (f16)(vsrc * 0.125f);
    }
  }
  *(f16x8*)((char*)hdst + (size_t)x * 16) = gout;
}

// ------------------- main fused kernel -------------------
// 128 blocks x 512 threads (8 waves, 2/SIMD). Wave w owns p in [4w, 4w+4).
// Chain folded into MFMA K-dim: A = c*a*o (f16), B = H granules (ring-8 reg buffer).
// Per-t: MFMA phase -> LDS partial write -> reduce -> next c. No shuffles.
__launch_bounds__(512, 2)
__global__ void k_main(const f16* __restrict__ aenc, const f16* __restrict__ oenc,
                       const char* __restrict__ hws, float* __restrict__ out) {
  __shared__ __align__(16) float cpart[8][32][40];  // [wave][p=l-col][b], pad 40
  __shared__ float cfull[32][40];                   // [p][b]

  const int tid  = threadIdx.x;
  const int lane = tid & 63;
  const int w    = tid >> 6;       // 0..7
  const int m16  = lane & 15;
  const int g4   = lane >> 4;      // 0..3
  const int b0   = blockIdx.x * BTILE;

  // init chain state: c[p][b] = (p == 0)
  #pragma unroll
  for (int rep = 0; rep < 2; ++rep) {
    const int e = tid + rep * 512;
    cfull[e >> 5][e & 31] = ((e >> 5) == 0) ? 1.f : 0.f;
  }

  const char* hlane = hws + (size_t)w * 65536 + (size_t)lane * 16;

  // prologue: preload ring with Q = 0..7
  f16x8 rb[8][2];
  #pragma unroll
  for (int q0 = 0; q0 < 8; ++q0) {
    rb[q0][0] = *(const f16x8*)(hlane + q0 * 2048);
    rb[q0][1] = *(const f16x8*)(hlane + q0 * 2048 + 1024);
  }
  __syncthreads();

  #pragma clang loop unroll(disable)
  for (int t = 0; t < T_; ++t) {
    // per-lane E inputs for both m-frags (b = mf*16 + m16)
    const f16* ap0 = aenc + ((size_t)(b0 + m16) * 32 + t) * 16;
    const f16* ap1 = aenc + ((size_t)(b0 + 16 + m16) * 32 + t) * 16;
    const f16x8 al0 = *(const f16x8*)ap0, ah0 = *(const f16x8*)(ap0 + 8);
    const f16x8 al1 = *(const f16x8*)ap1, ah1 = *(const f16x8*)(ap1 + 8);
    f16 a16[2][16];
    #pragma unroll
    for (int e = 0; e < 8; ++e) {
      a16[0][e] = al0[e]; a16[0][8 + e] = ah0[e];
      a16[1][e] = al1[e]; a16[1][8 + e] = ah1[e];
    }
    const f16x4 ov0 = *(const f16x4*)(oenc + ((size_t)(b0 + m16) * 32 + t) * 16 + g4 * 4);
    const f16x4 ov1 = *(const f16x4*)(oenc + ((size_t)(b0 + 16 + m16) * 32 + t) * 16 + g4 * 4);

    // chain-state reads: c[b=mf*16+m16][p=w*4+pp]
    f16 cf[4][2];
    #pragma unroll
    for (int pp = 0; pp < 4; ++pp) {
      cf[pp][0] = (f16)cfull[w * 4 + pp][m16];
      cf[pp][1] = (f16)cfull[w * 4 + pp][16 + m16];
    }

    f32x4 acc[2][2];
    #pragma unroll
    for (int mf = 0; mf < 2; ++mf)
      #pragma unroll
      for (int nf = 0; nf < 2; ++nf) acc[mf][nf] = (f32x4){0.f, 0.f, 0.f, 0.f};

    // ---- MFMA phase: 32 iterations (pp, s), ring-8 prefetch ----
    #pragma unroll
    for (int pp = 0; pp < 4; ++pp) {
      const f16 c0 = cf[pp][0], c1 = cf[pp][1];
      #pragma unroll
      for (int s = 0; s < 8; ++s) {
        const int q = pp * 8 + s;
        const f16 a00 = c0 * a16[0][2 * s], a01 = c0 * a16[0][2 * s + 1];
        const f16 a10 = c1 * a16[1][2 * s], a11 = c1 * a16[1][2 * s + 1];
        f16x8 af0, af1;
        #pragma unroll
        for (int r = 0; r < 4; ++r) {
          af0[r] = a00 * ov0[r]; af0[4 + r] = a01 * ov0[r];
          af1[r] = a10 * ov1[r]; af1[4 + r] = a11 * ov1[r];
        }
        acc[0][0] = __builtin_amdgcn_mfma_f32_16x16x32_f16(af0, rb[q & 7][0], acc[0][0], 0, 0, 0);
        acc[0][1] = __builtin_amdgcn_mfma_f32_16x16x32_f16(af0, rb[q & 7][1], acc[0][1], 0, 0, 0);
        acc[1][0] = __builtin_amdgcn_mfma_f32_16x16x32_f16(af1, rb[q & 7][0], acc[1][0], 0, 0, 0);
        acc[1][1] = __builtin_amdgcn_mfma_f32_16x16x32_f16(af1, rb[q & 7][1], acc[1][1], 0, 0, 0);
        // prefetch Q+8 into the slot just consumed (clamped at the very end)
        int Qn = t * 32 + q + 8;
        if (Qn > 1023) Qn = 1023;
        const char* pa = hlane + (size_t)(Qn >> 5) * 524288 + (size_t)(Qn & 31) * 2048;
        rb[q & 7][0] = *(const f16x8*)pa;
        rb[q & 7][1] = *(const f16x8*)(pa + 1024);
      }
    }

    // ---- chain phase: write partials, reduce across waves ----
    // D: col = m16 = l within nf ; rows = mf*16 + g4*4 + r
    #pragma unroll
    for (int mf = 0; mf < 2; ++mf)
      #pragma unroll
      for (int nf = 0; nf < 2; ++nf)
        *(f32x4*)&cpart[w][nf * 16 + m16][mf * 16 + g4 * 4] = acc[mf][nf];
    __syncthreads();
    #pragma unroll
    for (int rep = 0; rep < 2; ++rep) {
      const int e = tid + rep * 512;
      const int p = e >> 5, bb = e & 31;
      float ssum = 0.f;
      #pragma unroll
      for (int ww = 0; ww < 8; ++ww) ssum += cpart[ww][p][bb];
      if (t < 31) cfull[p][bb] = ssum;
      else if (p < 8) out[(size_t)(b0 + bb) * 8 + p] = ssum * 0x1p96f;  // undo 8^-32 scaling
    }
    __syncthreads();
  }
}

extern "C" void kernel_launch(void* const* d_in, const int* in_sizes, int n_in,
                              void* d_out, int out_size, void* d_ws, size_t ws_size,
                              hipStream_t stream) {
  (void)in_sizes; (void)n_in; (void)out_size; (void)ws_size;
  const float* action = (const float*)d_in[0];
  const float* obs    = (const float*)d_in[1];
  const float* Wa0 = (const float*)d_in[2];
  const float* ba0 = (const float*)d_in[3];
  const float* Wa1 = (const float*)d_in[4];
  const float* ba1 = (const float*)d_in[5];
  const float* Wo0 = (const float*)d_in[6];
  const float* bo0 = (const float*)d_in[7];
  const float* Wo1 = (const float*)d_in[8];
  const float* bo1 = (const float*)d_in[9];
  const float* Hf  = (const float*)d_in[10];
  const float* Hm  = (const float*)d_in[11];
  const float* Hl  = (const float*)d_in[12];
  char*  ws  = (char*)d_ws;
  float* out = (float*)d_out;

  k_fuse_w<<<1, 256, 0, stream>>>(Wa0, ba0, Wa1, ba1, Wo0, bo0, Wo1, bo1, (float*)ws);
  k_encode<<<(B_ * T_) / 64, 256, 0, stream>>>(action, obs, (const float*)ws,
                                               (f16*)(ws + WS_AENC), (f16*)(ws + WS_OENC));
  k_hprep<<<4096, 256, 0, stream>>>(Hf, Hm, Hl, (f16*)(ws + WS_H));
  k_main<<<NBLK, 512, 0, stream>>>((const f16*)(ws + WS_AENC), (const f16*)(ws + WS_OENC),
                                   (const char*)(ws + WS_H), out);
}